// Round 5
// baseline (261.450 us; speedup 1.0000x reference)
//
#include <hip/hip_runtime.h>

// LaBramChannelPatcher: [B=16, W=32, T=1000, C=64] fp32 ->
//   patches [B, W, C*nt=320, P=200]  (== per-(b,w) transpose [T,C] -> [C,T])
//   channel_indices [320] = repeat(arange(64), 5)
//   time_indices    [320] = tile(arange(5), 64)
//
// Round-5: NO-LDS in-register 4x4 transpose (discriminating experiment:
// rounds 0-4 all used LDS staging + barrier and all landed at 83-90 us
// regardless of conflicts/occupancy/traffic fixes; the barrier's vmcnt(0)
// drain couples every wave's stores to the block's slowest load, and every
// byte crosses LDS twice).
//
//  - Lane owns a 4x4 float block: 4 coalesced dwordx4 loads at consecutive t
//    (wave instr = 4 x 256B aligned extents, 16 full lines), transpose by
//    register renaming (zero ALU), 4 dwordx4 stores along t (wave instr =
//    16 channels x 64B contiguous).
//  - Wave tile = [16 t x 64 c]; 63 tiles per bw with the last at t0=984
//    (8-row overlap, idempotent duplicate writes -> no predication).
//  - No LDS, no barrier: loads/stores of all resident waves interleave
//    freely; 32 waves/CU.

#define PATCH_ELEMS 32768000    // 16*32*320*200
#define NTILES_T 63             // t0 = ti*16, last tile clamped to 984
#define TOTAL_TILES (512 * NTILES_T)   // 32256 wave-tiles

__global__ __launch_bounds__(256) void labram_patcher_kernel(
    const float* __restrict__ in, float* __restrict__ out)
{
    const int lane = threadIdx.x & 63;
    const int tq   = lane >> 4;    // 0..3  t-subgroup (4 t each)
    const int cq   = lane & 15;    // 0..15 channel quad
    const int wid    = (blockIdx.x * 256 + threadIdx.x) >> 6;  // global wave
    const int nwaves = (gridDim.x * 256) >> 6;

    for (int tile = wid; tile < TOTAL_TILES; tile += nwaves) {
        const int bw = tile / NTILES_T;          // 0..511
        const int ti = tile - bw * NTILES_T;     // 0..62
        const int t0 = (ti < 62) ? ti * 16 : 984;
        const int tr = t0 + tq * 4;              // this lane's first t-row

        // ---- 4 coalesced reads: rows tr..tr+3, cols cq*4..cq*4+3 ----
        const float4* src = (const float4*)in
                          + (size_t)bw * 16000 + (size_t)tr * 16 + cq;
        const float4 r0 = src[0];
        const float4 r1 = src[16];
        const float4 r2 = src[32];
        const float4 r3 = src[48];

        // ---- register-renaming transpose + 4 stores along t ----
        // out[c][t] for c = cq*4+j, t = tr..tr+3
        float4* dst = (float4*)out
                    + (size_t)bw * 16000 + (size_t)(cq * 4) * 250
                    + (t0 >> 2) + tq;
        dst[0]   = make_float4(r0.x, r1.x, r2.x, r3.x);
        dst[250] = make_float4(r0.y, r1.y, r2.y, r3.y);
        dst[500] = make_float4(r0.z, r1.z, r2.z, r3.z);
        dst[750] = make_float4(r0.w, r1.w, r2.w, r3.w);
    }

    // ---- Index outputs (tiny): block 0, grid-stride over 320 ----
    if (blockIdx.x == 0) {
        for (int i = threadIdx.x; i < 320; i += 256) {
            out[PATCH_ELEMS + i]       = (float)(i / 5);  // channel_indices
            out[PATCH_ELEMS + 320 + i] = (float)(i % 5);  // time_indices
        }
    }
}

extern "C" void kernel_launch(void* const* d_in, const int* in_sizes, int n_in,
                              void* d_out, int out_size, void* d_ws, size_t ws_size,
                              hipStream_t stream) {
    const float* in = (const float*)d_in[0];
    float* out = (float*)d_out;
    dim3 grid(2048);    // 8 blocks/CU, 32 waves/CU; ~4 tiles per wave
    dim3 block(256);
    labram_patcher_kernel<<<grid, block, 0, stream>>>(in, out);
}

// Round 7
// 241.308 us; speedup vs baseline: 1.0835x; 1.0835x over previous
//
#include <hip/hip_runtime.h>

// LaBramChannelPatcher: [B=16, W=32, T=1000, C=64] fp32 ->
//   patches [B, W, C*nt=320, P=200]  (== per-(b,w) transpose [T,C] -> [C,T])
//   channel_indices [320] = repeat(arange(64), 5)
//   time_indices    [320] = tile(arange(5), 64)
//
// Round-7 = round-6 with the bw-stride bug fixed (per-bw slab is 64,000
// floats = 16,000 float4; round 6 used bw*4000 on both sides -> wrong slab).
//
// Round-6 design (request-rate theory, still under test): full cache-line
// granularity, block-exclusive, on BOTH sides simultaneously.
//  - Block = (bw, t-tile of 64): reads = 4 rows x 256 B aligned full-line
//    extents per wave instr, zero cross-block read sharing.
//  - Writes: 64 channels x 256 B aligned contiguous chunks (16 float4 by 16
//    consecutive lanes), block-exclusive. Tail tile (t0=960, nt=40) writes
//    160 B/channel -> shares only channel-boundary lines (~3%).
//  - LDS [64 c][64 t] padded stride 65: every scalar ds access is exactly
//    2 lanes/bank (free). 16.6 KB -> 8 blocks/CU, 32 waves/CU.
//  - XCD-chunk swizzle keeps all 16 tiles of one bw on one XCD.

#define TDIM 1000
#define CDIM 64
#define LSTR 65
#define PATCH_ELEMS 32768000    // 16*32*320*200

__global__ __launch_bounds__(256, 8) void labram_patcher_kernel(
    const float* __restrict__ in, float* __restrict__ out)
{
    __shared__ float lds[CDIM * LSTR];   // [c][t], 16,640 B

    const int tid  = threadIdx.x;
    const int phys = blockIdx.x;
    // bijective XCD-chunk swizzle (8192 blocks = 8 XCDs * 1024):
    // 16 consecutive virt (one bw) -> same XCD.
    const int virt = (phys & 7) * 1024 + (phys >> 3);
    const int bw = virt >> 4;            // 0..511  (b*32 + w)
    const int ti = virt & 15;            // t-tile 0..15
    const int t0 = (ti < 15) ? ti * 64 : 960;
    const int nt = (ti < 15) ? 64 : 40;  // rows in this tile

    // ---- Phase 1: full-line loads (4 rows x 256 B per wave instr),
    //      scatter-transpose into lds[c][t] (2 lanes/bank). ----
    const float4* src4 = (const float4*)in + (size_t)bw * 16000 + (size_t)t0 * 16;

    float4 v[4];
    int tr[4];
    #pragma unroll
    for (int k = 0; k < 4; ++k) {
        const int i = tid + k * 256;
        tr[k] = i >> 4;                  // row within tile, 0..63
        if (tr[k] < nt)
            v[k] = src4[tr[k] * 16 + (i & 15)];
    }
    #pragma unroll
    for (int k = 0; k < 4; ++k) {
        const int i = tid + k * 256;
        const int u = i & 15;            // 16B unit in row -> channels 4u..4u+3
        if (tr[k] < nt) {
            lds[(4 * u + 0) * LSTR + tr[k]] = v[k].x;
            lds[(4 * u + 1) * LSTR + tr[k]] = v[k].y;
            lds[(4 * u + 2) * LSTR + tr[k]] = v[k].z;
            lds[(4 * u + 3) * LSTR + tr[k]] = v[k].w;
        }
    }
    __syncthreads();

    // ---- Phase 2: gather rows of lds[c][*] (scalar reads, 2 lanes/bank),
    //      256-B aligned contiguous float4 stores: 16 consecutive lanes
    //      cover one channel's 64-t chunk. ----
    float4* dst4 = (float4*)out + (size_t)bw * 16000 + (t0 >> 2);

    #pragma unroll
    for (int k = 0; k < 4; ++k) {
        const int i = tid + k * 256;
        const int c = i >> 4;            // 0..63
        const int u = i & 15;            // float4 unit along t
        if (4 * u < nt) {
            const int b = c * LSTR + 4 * u;
            float4 w;
            w.x = lds[b + 0];
            w.y = lds[b + 1];
            w.z = lds[b + 2];
            w.w = lds[b + 3];
            dst4[(size_t)c * 250 + u] = w;
        }
    }

    // ---- Index outputs (tiny): one block, grid-stride over 320 ----
    if (phys == 0) {
        for (int i = tid; i < 320; i += 256) {
            out[PATCH_ELEMS + i]       = (float)(i / 5);  // channel_indices
            out[PATCH_ELEMS + 320 + i] = (float)(i % 5);  // time_indices
        }
    }
}

extern "C" void kernel_launch(void* const* d_in, const int* in_sizes, int n_in,
                              void* d_out, int out_size, void* d_ws, size_t ws_size,
                              hipStream_t stream) {
    const float* in = (const float*)d_in[0];
    float* out = (float*)d_out;
    dim3 grid(512 * 16);   // 512 (b,w) slices * 16 t-tiles
    dim3 block(256);
    labram_patcher_kernel<<<grid, block, 0, stream>>>(in, out);
}